// Round 6
// baseline (383.561 us; speedup 1.0000x reference)
//
#include <hip/hip_runtime.h>

// Problem constants: B=16, P=1024, E=1024, H=16, DH=64
#define PB 16
#define PP 1024
#define PE 1024
#define PH 16
#define PDH 64

typedef __attribute__((ext_vector_type(8))) short bf16x8;
typedef __attribute__((ext_vector_type(4))) short bf16x4;
typedef __attribute__((ext_vector_type(4))) float f32x4;

#define LOG2E 1.44269504088896340736f

__device__ __forceinline__ short f2bf(float f) {
    union { float f; unsigned u; } a;
    a.f = f;
    unsigned u = a.u;
    u += 0x7fffu + ((u >> 16) & 1u);   // round-to-nearest-even
    return (short)(u >> 16);
}
__device__ __forceinline__ float bf2f(short s) {
    union { unsigned u; float f; } a;
    a.u = ((unsigned)(unsigned short)s) << 16;
    return a.f;
}
// pack two f32 -> one dword of 2 bf16 (src0 in low half)
__device__ __forceinline__ unsigned cvtpk(float lo, float hi) {
    unsigned r;
    asm("v_cvt_pk_bf16_f32 %0, %1, %2" : "=v"(r) : "v"(lo), "v"(hi));
    return r;
}
union U8 { unsigned u[4]; bf16x8 v; };
// LDS-only barrier: orders ds ops, does NOT drain vmcnt — global prefetches
// stay in flight across it (valid because staging here is reg->LDS, never
// global_load_lds; the consuming ds_write gets a compiler vmcnt(N)).
__device__ __forceinline__ void barrier_lds() {
    asm volatile("s_waitcnt lgkmcnt(0)\n\ts_barrier" ::: "memory");
}
// async global->LDS, 16B per lane; LDS dest = wave-uniform base + lane*16
__device__ __forceinline__ void async16(const void* g, void* l) {
    __builtin_amdgcn_global_load_lds(
        (const __attribute__((address_space(1))) unsigned int*)g,
        (__attribute__((address_space(3))) unsigned int*)l, 16, 0, 0);
}

// ---------------------------------------------------------------------------
// Kernel 0a: bias_prep — bf16(bias*log2e) pre-blocked into flash's exact
// per-(tile,wave,lane) fragment order. Flash then reads 4 coalesced 16B
// loads per thread per tile.
// Layout: biasP[h][tile][qblk][wave][j=kt(4)][lane(64)][8 shorts]
//   lane (lq,lm), short idx = qt*4 + r  ->
//   element (q = qblk*128 + wave*32 + qt*16 + lm, kv = tile*64 + kt*16 + lq*4 + r)
// ---------------------------------------------------------------------------
__global__ __launch_bounds__(256) void bias_prep(const float* __restrict__ bias,
                                                 short* __restrict__ biasP) {
    int bid = blockIdx.x;                       // grid 2048 = 16h * 8qblk * 16tile
    int h = bid >> 7, qblk = (bid >> 4) & 7, tile = bid & 15;
    int q0 = qblk * 128, kv0 = tile * 64;
    __shared__ short T[128][68];                // T[qrel][kvrel], 8B-aligned rows

    int t = threadIdx.x;
    {
        int qr = t >> 1, half = t & 1;
        const float* src = bias + ((size_t)h << 20) + (size_t)(q0 + qr) * 1024 + kv0 + half * 32;
#pragma unroll
        for (int i = 0; i < 32; i += 4) {
            float4 v = *(const float4*)(src + i);
            bf16x4 p = {f2bf(v.x * LOG2E), f2bf(v.y * LOG2E), f2bf(v.z * LOG2E), f2bf(v.w * LOG2E)};
            *(bf16x4*)&T[qr][half * 32 + i] = p;
        }
    }
    __syncthreads();

    int w = t >> 6, l = t & 63, lm = l & 15, lq = l >> 4;
    short* dst = biasP + (((size_t)(h * 16 + tile) * 8 + qblk) * 4 + w) * 2048 + l * 8;
#pragma unroll
    for (int j = 0; j < 4; j++) {
        bf16x4 a = *(const bf16x4*)&T[w * 32 + lm][j * 16 + lq * 4];        // qt=0
        bf16x4 b = *(const bf16x4*)&T[w * 32 + 16 + lm][j * 16 + lq * 4];   // qt=1
        bf16x8 o = {a[0], a[1], a[2], a[3], b[0], b[1], b[2], b[3]};
        *(bf16x8*)(dst + j * 512) = o;
    }
}

// ---------------------------------------------------------------------------
// Kernel 0b: weight fp32 -> bf16 (wv_w and out_w, both [n][k] row-major)
// ---------------------------------------------------------------------------
__global__ __launch_bounds__(256) void wconv(const float* __restrict__ wvw,
                                             const float* __restrict__ outw,
                                             short* __restrict__ wvwb,
                                             short* __restrict__ outwb) {
    int bid = blockIdx.x;
    const float* src = (bid < 512) ? wvw : outw;
    short* dst = (bid < 512) ? wvwb : outwb;
    int lb = (bid < 512) ? bid : bid - 512;
    size_t idx = ((size_t)lb * 256 + threadIdx.x) * 8;
    float4 a = *(const float4*)(src + idx);
    float4 b = *(const float4*)(src + idx + 4);
    bf16x8 t = {f2bf(a.x), f2bf(a.y), f2bf(a.z), f2bf(a.w),
                f2bf(b.x), f2bf(b.y), f2bf(b.z), f2bf(b.w)};
    *(bf16x8*)(dst + idx) = t;
}

// ---------------------------------------------------------------------------
// Kernel 1: xw = (x_h @ w_att_val[h]) * 0.125 * log2e (bf16)  AND  xbf = bf16(x)
// ---------------------------------------------------------------------------
__global__ __launch_bounds__(256) void xw_kernel(const float* __restrict__ x,
                                                 const float* __restrict__ watt,
                                                 short* __restrict__ xw,
                                                 short* __restrict__ xbf) {
    int bid = blockIdx.x;
    int q4 = bid & 3;
    int bh = bid >> 2;          // b*16 + h
    int h = bh & 15;
    __shared__ short Wt[64][88];   // W^T: Wt[e'][d]

    int tid = threadIdx.x;
    {
        const float* W = watt + (size_t)h * 4096;
        int idx = tid * 16;
        int d = idx >> 6, e0 = idx & 63;
#pragma unroll
        for (int i = 0; i < 16; i += 4) {
            float4 v = *(const float4*)(W + d * 64 + e0 + i);
            Wt[e0 + i + 0][d] = f2bf(v.x);
            Wt[e0 + i + 1][d] = f2bf(v.y);
            Wt[e0 + i + 2][d] = f2bf(v.z);
            Wt[e0 + i + 3][d] = f2bf(v.w);
        }
    }
    __syncthreads();

    int wave = tid >> 6, lane = tid & 63;
    int lm = lane & 15, lq = lane >> 4;

    bf16x8 bfr[4][2];
#pragma unroll
    for (int nt = 0; nt < 4; nt++)
#pragma unroll
        for (int kf = 0; kf < 2; kf++)
            bfr[nt][kf] = *(const bf16x8*)&Wt[nt * 16 + lm][kf * 32 + lq * 8];

    int b = bh >> 4;
    const float QSCALE = 0.125f * LOG2E;
    for (int pass = 0; pass < 4; pass++) {
        int p0 = q4 * 256 + pass * 64 + wave * 16;
        const float* xrow = x + ((size_t)(b * 1024 + p0 + lm)) * 1024 + h * 64;
        short* xorow = xbf + ((size_t)(b * 1024 + p0 + lm)) * 1024 + h * 64;
        bf16x8 af[2];
#pragma unroll
        for (int kf = 0; kf < 2; kf++) {
            float4 v0 = *(const float4*)(xrow + kf * 32 + lq * 8);
            float4 v1 = *(const float4*)(xrow + kf * 32 + lq * 8 + 4);
            bf16x8 t;
            t[0] = f2bf(v0.x); t[1] = f2bf(v0.y); t[2] = f2bf(v0.z); t[3] = f2bf(v0.w);
            t[4] = f2bf(v1.x); t[5] = f2bf(v1.y); t[6] = f2bf(v1.z); t[7] = f2bf(v1.w);
            af[kf] = t;
            *(bf16x8*)(xorow + kf * 32 + lq * 8) = t;   // bf16 copy of x
        }
#pragma unroll
        for (int nt = 0; nt < 4; nt++) {
            f32x4 acc = {0.f, 0.f, 0.f, 0.f};
            acc = __builtin_amdgcn_mfma_f32_16x16x32_bf16(af[0], bfr[nt][0], acc, 0, 0, 0);
            acc = __builtin_amdgcn_mfma_f32_16x16x32_bf16(af[1], bfr[nt][1], acc, 0, 0, 0);
            size_t base = ((size_t)bh * 1024 + p0 + lq * 4) * 64 + nt * 16 + lm;
#pragma unroll
            for (int r = 0; r < 4; r++)
                xw[base + (size_t)r * 64] = f2bf(acc[r] * QSCALE);
        }
    }
}

// ---------------------------------------------------------------------------
// Kernel 2: vt[b,h,d,p] = (x @ wv_w^T + wv_b) transposed (bf16), with the
// per-32-col permutation p' = g*8 + h2*4 + r (orig p = h2*16 + g*4 + r) so
// flash can read V fragments as single b128s. XCD-swizzled grid.
// ---------------------------------------------------------------------------
__global__ __launch_bounds__(256) void vx_gemm(const short* __restrict__ xbf,
                                               const short* __restrict__ wvwb,
                                               const float* __restrict__ wvb,
                                               short* __restrict__ vt) {
    int logical = (blockIdx.x & 7) * 128 + (blockIdx.x >> 3);   // grid 1024 = 8*128
    int mblk = logical >> 3, nblk = logical & 7;
    int m0 = mblk * 128, n0 = nblk * 128;
    __shared__ short As[128 * 32];
    __shared__ short Bs[128 * 32];

    int tid = threadIdx.x;
    int wv = tid >> 6, ln = tid & 63;
    int c0 = wv * 2;
    int rrow = ln >> 2, rseg = (ln & 3) * 8;
    const short* gA = xbf + (size_t)(m0 + c0 * 16 + rrow) * 1024 + rseg;
    const short* gB = wvwb + (size_t)(n0 + c0 * 16 + rrow) * 1024 + rseg;
    short* lA = As + c0 * 512;
    short* lB = Bs + c0 * 512;

    int lane = ln, lm = lane & 15, lq = lane >> 4;
    int wm = (wv >> 1) * 64, wn = (wv & 1) * 64;

    f32x4 acc[4][4];
#pragma unroll
    for (int i = 0; i < 4; i++)
#pragma unroll
        for (int j = 0; j < 4; j++) acc[i][j] = (f32x4){0.f, 0.f, 0.f, 0.f};

    for (int k0 = 0; k0 < 1024; k0 += 32) {
        __syncthreads();
        async16(gA + k0, lA);
        async16(gA + k0 + 16 * 1024, lA + 512);
        async16(gB + k0, lB);
        async16(gB + k0 + 16 * 1024, lB + 512);
        __syncthreads();
        bf16x8 af[4], bfr[4];
#pragma unroll
        for (int mt = 0; mt < 4; mt++) af[mt] = *(const bf16x8*)&As[(wm + mt * 16 + lm) * 32 + lq * 8];
#pragma unroll
        for (int nt = 0; nt < 4; nt++) bfr[nt] = *(const bf16x8*)&Bs[(wn + nt * 16 + lm) * 32 + lq * 8];
#pragma unroll
        for (int mt = 0; mt < 4; mt++)
#pragma unroll
            for (int nt = 0; nt < 4; nt++)
                acc[mt][nt] = __builtin_amdgcn_mfma_f32_16x16x32_bf16(af[mt], bfr[nt], acc[mt][nt], 0, 0, 0);
    }

#pragma unroll
    for (int nt = 0; nt < 4; nt++) {
        int e = n0 + wn + nt * 16 + lm;
        float bias = wvb[e];
        int hh = e >> 6, dd = e & 63;
#pragma unroll
        for (int mt = 0; mt < 4; mt++) {
            int pg = m0 + wm + mt * 16 + lq * 4;
            // V column permute within each 32-block: orig (h2=mt&1, g=lq, r)
            // stored at g*8 + h2*4 + r
            int ppn = (pg & ~31) + lq * 8 + (mt & 1) * 4;
            int bb = ppn >> 10, pp = ppn & 1023;
            bf16x4 pk;
#pragma unroll
            for (int r = 0; r < 4; r++) pk[r] = f2bf(acc[mt][nt][r] + bias);
            *(bf16x4*)(vt + ((size_t)((bb * 16 + hh) * 64 + dd)) * 1024 + pp) = pk;
        }
    }
}

// ---------------------------------------------------------------------------
// Kernel 3: flash attention v9 — v8 + MFMA-ones row-sum: the softmax
// denominator is accumulated on the matrix pipe (P @ ones) in the exact o[]
// accumulator layout, deleting the per-tile VALU adds, the epilogue
// butterfly, the Rs LDS round-trip, and the final sync. Numerator and
// denominator now both sum the same bf16-rounded P.
// ---------------------------------------------------------------------------
__global__ __launch_bounds__(256, 3) void flash_kernel(const short* __restrict__ xbf,
                                                       const short* __restrict__ xw,
                                                       const short* __restrict__ vt,
                                                       const short* __restrict__ biasP,
                                                       short* __restrict__ obuf) {
    int logical = (blockIdx.x & 7) * 256 + (blockIdx.x >> 3);
    int qblk = logical & 7, b = (logical >> 3) & 15, h = logical >> 7;
    int bh = b * 16 + h;
    int q0 = qblk * 128;

    __shared__ short Ks[2][64 * 72];   // K[kv][d], row stride 72
    __shared__ short Vs[2][64 * 72];   // V^T[d][kv-permuted], row stride 72

    int tid = threadIdx.x, wave = tid >> 6, lane = tid & 63;
    int lm = lane & 15, lq = lane >> 4;

    // Q fragments: B-operand of the swapped QK^T (lane lm = q column).
    bf16x8 qa[2][2];
#pragma unroll
    for (int qt = 0; qt < 2; qt++)
#pragma unroll
        for (int kf = 0; kf < 2; kf++)
            qa[qt][kf] = *(const bf16x8*)(xw + ((size_t)bh * 1024 + q0 + wave * 32 + qt * 16 + lm) * 64 + kf * 32 + lq * 8);

    f32x4 o[2][4];
#pragma unroll
    for (int qt = 0; qt < 2; qt++)
#pragma unroll
        for (int dt = 0; dt < 4; dt++) o[qt][dt] = (f32x4){0.f, 0.f, 0.f, 0.f};
    // row-sum accumulators on the MFMA pipe: osum[qt][r] = sum_kv P for
    // q = qt*16 + lq*4 + r (value replicated across lm columns)
    f32x4 osum[2];
    osum[0] = (f32x4){0.f, 0.f, 0.f, 0.f};
    osum[1] = (f32x4){0.f, 0.f, 0.f, 0.f};
    const short ONE = 0x3F80;          // 1.0 bf16
    const bf16x8 vones = {ONE, ONE, ONE, ONE, ONE, ONE, ONE, ONE};

    // staging maps: thread stages 2x bf16x8 for K and 2 for V
    int ci0 = tid * 2, ci1 = tid * 2 + 1;
    int r0 = ci0 >> 3, s0 = (ci0 & 7) * 8;
    int r1 = ci1 >> 3, s1 = (ci1 & 7) * 8;
    const short* kg = xbf + ((size_t)(b * 1024)) * 1024 + h * 64;   // + (kv0+row)*1024 + seg
    const short* vg = vt + ((size_t)bh * 64) * 1024;                // + row*1024 + kv0 + seg
    // pre-blocked bf16 bias: per tile, 4 coalesced 16B loads per thread
    const short* bg = biasP + (((size_t)(h * 16) * 8 + qblk) * 4 + wave) * 2048 + lane * 8;
    const size_t BT_STRIDE = 65536;   // 8qblk*4wave*2048 shorts per tile

    bf16x8 kr[2], vr[2], br[4];
    // prologue: tile 0 -> LDS buf0; tile 1 -> regs; bias tile 0 -> regs
    kr[0] = *(const bf16x8*)(kg + (size_t)r0 * 1024 + s0);
    kr[1] = *(const bf16x8*)(kg + (size_t)r1 * 1024 + s1);
    vr[0] = *(const bf16x8*)(vg + (size_t)r0 * 1024 + s0);
    vr[1] = *(const bf16x8*)(vg + (size_t)r1 * 1024 + s1);
    *(bf16x8*)&Ks[0][r0 * 72 + s0] = kr[0];
    *(bf16x8*)&Ks[0][r1 * 72 + s1] = kr[1];
    *(bf16x8*)&Vs[0][r0 * 72 + s0] = vr[0];
    *(bf16x8*)&Vs[0][r1 * 72 + s1] = vr[1];
    kr[0] = *(const bf16x8*)(kg + (size_t)(64 + r0) * 1024 + s0);
    kr[1] = *(const bf16x8*)(kg + (size_t)(64 + r1) * 1024 + s1);
    vr[0] = *(const bf16x8*)(vg + (size_t)r0 * 1024 + 64 + s0);
    vr[1] = *(const bf16x8*)(vg + (size_t)r1 * 1024 + 64 + s1);
#pragma unroll
    for (int kt = 0; kt < 4; kt++)
        br[kt] = *(const bf16x8*)(bg + kt * 512);

    for (int tile = 0; tile < 16; tile++) {
        const int cur = tile & 1;
        const short* Kc = Ks[cur];
        const short* Vc = Vs[cur];
        short* Kn = Ks[cur ^ 1];
        short* Vn = Vs[cur ^ 1];

        barrier_lds();   // separates last-readers of buf[cur^1] from its writers

        // stage tile+1 (in regs) into the other buffer
        if (tile < 15) {
            *(bf16x8*)&Kn[r0 * 72 + s0] = kr[0];
            *(bf16x8*)&Kn[r1 * 72 + s1] = kr[1];
            *(bf16x8*)&Vn[r0 * 72 + s0] = vr[0];
            *(bf16x8*)&Vn[r1 * 72 + s1] = vr[1];
        }
        // issue tile+2 global loads (consumed at next iter's stage)
        if (tile < 14) {
            int kvn = (tile + 2) * 64;
            kr[0] = *(const bf16x8*)(kg + (size_t)(kvn + r0) * 1024 + s0);
            kr[1] = *(const bf16x8*)(kg + (size_t)(kvn + r1) * 1024 + s1);
            vr[0] = *(const bf16x8*)(vg + (size_t)r0 * 1024 + kvn + s0);
            vr[1] = *(const bf16x8*)(vg + (size_t)r1 * 1024 + kvn + s1);
        }

        // acc init from prefetched bias regs:
        // s[kt][qt] elem r -> (kv = kv0+kt*16+lq*4+r, q = q0+wave*32+qt*16+lm)
        f32x4 s[4][2];
#pragma unroll
        for (int kt = 0; kt < 4; kt++)
#pragma unroll
            for (int qt = 0; qt < 2; qt++)
                s[kt][qt] = (f32x4){bf2f(br[kt][qt * 4 + 0]), bf2f(br[kt][qt * 4 + 1]),
                                    bf2f(br[kt][qt * 4 + 2]), bf2f(br[kt][qt * 4 + 3])};

        // issue next tile's bias ASAP (br just consumed; T14 issue-early)
        if (tile < 15) {
            const short* bgn = bg + (size_t)(tile + 1) * BT_STRIDE;
#pragma unroll
            for (int kt = 0; kt < 4; kt++)
                br[kt] = *(const bf16x8*)(bgn + kt * 512);
        }

        // S^T = K Q^T + bias  (A = K rows=kv, B = Q cols=q)
#pragma unroll
        for (int kf = 0; kf < 2; kf++) {
            bf16x8 ka[4];
#pragma unroll
            for (int kt = 0; kt < 4; kt++)
                ka[kt] = *(const bf16x8*)&Kc[(kt * 16 + lm) * 72 + kf * 32 + lq * 8];
#pragma unroll
            for (int kt = 0; kt < 4; kt++)
#pragma unroll
                for (int qt = 0; qt < 2; qt++)
                    s[kt][qt] = __builtin_amdgcn_mfma_f32_16x16x32_bf16(ka[kt], qa[qt][kf], s[kt][qt], 0, 0, 0);
        }

        // fixed-max softmax in place: p = exp2(s)  (no VALU row-sum — the
        // denominator is accumulated by the ones-MFMA below)
#pragma unroll
        for (int kt = 0; kt < 4; kt++)
#pragma unroll
            for (int qt = 0; qt < 2; qt++) {
                s[kt][qt][0] = __builtin_amdgcn_exp2f(s[kt][qt][0]);
                s[kt][qt][1] = __builtin_amdgcn_exp2f(s[kt][qt][1]);
                s[kt][qt][2] = __builtin_amdgcn_exp2f(s[kt][qt][2]);
                s[kt][qt][3] = __builtin_amdgcn_exp2f(s[kt][qt][3]);
            }

        // O += P V; osum += P @ ones.  P stays in registers; V stored
        // permuted so the matching fragment is ONE b128 at col kf*32 + lq*8.
#pragma unroll
        for (int kf = 0; kf < 2; kf++) {
            bf16x8 pa[2];
#pragma unroll
            for (int qt = 0; qt < 2; qt++) {
                U8 u;
                u.u[0] = cvtpk(s[kf * 2][qt][0], s[kf * 2][qt][1]);
                u.u[1] = cvtpk(s[kf * 2][qt][2], s[kf * 2][qt][3]);
                u.u[2] = cvtpk(s[kf * 2 + 1][qt][0], s[kf * 2 + 1][qt][1]);
                u.u[3] = cvtpk(s[kf * 2 + 1][qt][2], s[kf * 2 + 1][qt][3]);
                pa[qt] = u.v;
                osum[qt] = __builtin_amdgcn_mfma_f32_16x16x32_bf16(pa[qt], vones, osum[qt], 0, 0, 0);
            }
#pragma unroll
            for (int dt = 0; dt < 4; dt++) {
                bf16x8 uv = *(const bf16x8*)&Vc[(dt * 16 + lm) * 72 + kf * 32 + lq * 8];
#pragma unroll
                for (int qt = 0; qt < 2; qt++)
                    o[qt][dt] = __builtin_amdgcn_mfma_f32_16x16x32_bf16(pa[qt], uv, o[qt][dt], 0, 0, 0);
            }
        }
    }

    // epilogue: osum[qt][r] already holds the denominator for
    // q = qt*16 + lq*4 + r (same D-layout as o). No shuffle, no LDS, no sync.
#pragma unroll
    for (int qt = 0; qt < 2; qt++) {
        float inv[4];
#pragma unroll
        for (int r = 0; r < 4; r++)
            inv[r] = 1.f / osum[qt][r];
#pragma unroll
        for (int dt = 0; dt < 4; dt++) {
            int e = h * 64 + dt * 16 + lm;
#pragma unroll
            for (int r = 0; r < 4; r++) {
                int p = q0 + wave * 32 + qt * 16 + lq * 4 + r;
                obuf[((size_t)(b * 1024 + p)) * 1024 + e] = f2bf(o[qt][dt][r] * inv[r]);
            }
        }
    }
}

// ---------------------------------------------------------------------------
// Kernel 4: out = obuf @ out_w^T + out_b (fp32). m97-style staging,
// XCD-swizzled grid.
// ---------------------------------------------------------------------------
__global__ __launch_bounds__(256) void out_gemm(const short* __restrict__ obuf,
                                                const short* __restrict__ outwb,
                                                const float* __restrict__ outb,
                                                float* __restrict__ out) {
    int logical = (blockIdx.x & 7) * 128 + (blockIdx.x >> 3);
    int mblk = logical >> 3, nblk = logical & 7;
    int m0 = mblk * 128, n0 = nblk * 128;
    __shared__ short As[128 * 32];
    __shared__ short Bs[128 * 32];

    int tid = threadIdx.x;
    int wv = tid >> 6, ln = tid & 63;
    int c0 = wv * 2;
    int rrow = ln >> 2, rseg = (ln & 3) * 8;
    const short* gA = obuf + (size_t)(m0 + c0 * 16 + rrow) * 1024 + rseg;
    const short* gB = outwb + (size_t)(n0 + c0 * 16 + rrow) * 1024 + rseg;
    short* lA = As + c0 * 512;
    short* lB = Bs + c0 * 512;

    int lm = ln & 15, lq = ln >> 4;
    int wm = (wv >> 1) * 64, wn = (wv & 1) * 64;

    f32x4 acc[4][4];
#pragma unroll
    for (int i = 0; i < 4; i++)
#pragma unroll
        for (int j = 0; j < 4; j++) acc[i][j] = (f32x4){0.f, 0.f, 0.f, 0.f};

    for (int k0 = 0; k0 < 1024; k0 += 32) {
        __syncthreads();
        async16(gA + k0, lA);
        async16(gA + k0 + 16 * 1024, lA + 512);
        async16(gB + k0, lB);
        async16(gB + k0 + 16 * 1024, lB + 512);
        __syncthreads();
        bf16x8 af[4], bfr[4];
#pragma unroll
        for (int mt = 0; mt < 4; mt++) af[mt] = *(const bf16x8*)&As[(wm + mt * 16 + lm) * 32 + lq * 8];
#pragma unroll
        for (int nt = 0; nt < 4; nt++) bfr[nt] = *(const bf16x8*)&Bs[(wn + nt * 16 + lm) * 32 + lq * 8];
#pragma unroll
        for (int mt = 0; mt < 4; mt++)
#pragma unroll
            for (int nt = 0; nt < 4; nt++)
                acc[mt][nt] = __builtin_amdgcn_mfma_f32_16x16x32_bf16(af[mt], bfr[nt], acc[mt][nt], 0, 0, 0);
    }

#pragma unroll
    for (int nt = 0; nt < 4; nt++) {
        int e = n0 + wn + nt * 16 + lm;
        float bias = outb[e];
#pragma unroll
        for (int mt = 0; mt < 4; mt++) {
            int pg = m0 + wm + mt * 16 + lq * 4;
#pragma unroll
            for (int r = 0; r < 4; r++)
                out[(size_t)(pg + r) * 1024 + e] = acc[mt][nt][r] + bias;
        }
    }
}

extern "C" void kernel_launch(void* const* d_in, const int* in_sizes, int n_in,
                              void* d_out, int out_size, void* d_ws, size_t ws_size,
                              hipStream_t stream) {
    const float* x    = (const float*)d_in[0];  // [16,1024,1024]
    const float* watt = (const float*)d_in[1];  // [16,64,64]
    const float* bias = (const float*)d_in[2];  // [16,1024,1024]
    const float* wvw  = (const float*)d_in[3];  // [1024,1024]
    const float* wvb  = (const float*)d_in[4];  // [1024]
    const float* outw = (const float*)d_in[5];  // [1024,1024]
    const float* outb = (const float*)d_in[6];  // [1024]
    float* out = (float*)d_out;

    char* ws = (char*)d_ws;
    short* xw     = (short*)ws;                           // 32 MB  [B,H,P,DH] bf16 (Q, pre-scaled 0.125*log2e)
    short* vt     = (short*)(ws + ((size_t)32 << 20));    // 32 MB  [B,H,DH,P] bf16 (V^T, col-permuted)
    short* obuf   = (short*)(ws + ((size_t)64 << 20));    // 32 MB  [B,P,E]    bf16 (attn out)
    short* xbf    = (short*)(ws + ((size_t)96 << 20));    // 32 MB  [B,P,E]    bf16 (x)
    short* biasP  = (short*)(ws + ((size_t)128 << 20));   // 32 MB  blocked bf16 bias*log2e
    short* wvwb   = (short*)(ws + ((size_t)160 << 20));   // 2 MB
    short* outwb  = (short*)(ws + ((size_t)162 << 20));   // 2 MB

    xw_kernel<<<PB * PH * 4, 256, 0, stream>>>(x, watt, xw, xbf);
    bias_prep<<<2048, 256, 0, stream>>>(bias, biasP);
    wconv<<<1024, 256, 0, stream>>>(wvw, outw, wvwb, outwb);
    vx_gemm<<<(PB * PP / 128) * (PE / 128), 256, 0, stream>>>(xbf, wvwb, wvb, vt);
    flash_kernel<<<PB * PH * (PP / 128), 256, 0, stream>>>(xbf, xw, vt, biasP, obuf);
    out_gemm<<<(PB * PP / 128) * (PE / 128), 256, 0, stream>>>(obuf, outwb, outb, out);
}

// Round 7
// 375.253 us; speedup vs baseline: 1.0221x; 1.0221x over previous
//
#include <hip/hip_runtime.h>

// Problem constants: B=16, P=1024, E=1024, H=16, DH=64
#define PB 16
#define PP 1024
#define PE 1024
#define PH 16
#define PDH 64

typedef __attribute__((ext_vector_type(8))) short bf16x8;
typedef __attribute__((ext_vector_type(4))) short bf16x4;
typedef __attribute__((ext_vector_type(4))) float f32x4;

#define LOG2E 1.44269504088896340736f

__device__ __forceinline__ short f2bf(float f) {
    union { float f; unsigned u; } a;
    a.f = f;
    unsigned u = a.u;
    u += 0x7fffu + ((u >> 16) & 1u);   // round-to-nearest-even
    return (short)(u >> 16);
}
__device__ __forceinline__ float bf2f(short s) {
    union { unsigned u; float f; } a;
    a.u = ((unsigned)(unsigned short)s) << 16;
    return a.f;
}
// pack two f32 -> one dword of 2 bf16 (src0 in low half)
__device__ __forceinline__ unsigned cvtpk(float lo, float hi) {
    unsigned r;
    asm("v_cvt_pk_bf16_f32 %0, %1, %2" : "=v"(r) : "v"(lo), "v"(hi));
    return r;
}
union U8 { unsigned u[4]; bf16x8 v; };
// LDS-only barrier: orders ds ops, does NOT drain vmcnt — global prefetches
// stay in flight across it (valid because staging here is reg->LDS, never
// global_load_lds; the consuming ds_write gets a compiler vmcnt(N)).
__device__ __forceinline__ void barrier_lds() {
    asm volatile("s_waitcnt lgkmcnt(0)\n\ts_barrier" ::: "memory");
}
// async global->LDS, 16B per lane; LDS dest = wave-uniform base + lane*16
__device__ __forceinline__ void async16(const void* g, void* l) {
    __builtin_amdgcn_global_load_lds(
        (const __attribute__((address_space(1))) unsigned int*)g,
        (__attribute__((address_space(3))) unsigned int*)l, 16, 0, 0);
}

// ---------------------------------------------------------------------------
// Kernel 0a: bias_prep — bf16(bias*log2e) pre-blocked into flash's exact
// per-(tile,wave,lane) fragment order. Flash then reads 4 coalesced 16B
// loads per thread per tile.
// Layout: biasP[h][tile][qblk][wave][j=kt(4)][lane(64)][8 shorts]
//   lane (lq,lm), short idx = qt*4 + r  ->
//   element (q = qblk*128 + wave*32 + qt*16 + lm, kv = tile*64 + kt*16 + lq*4 + r)
// ---------------------------------------------------------------------------
__global__ __launch_bounds__(256) void bias_prep(const float* __restrict__ bias,
                                                 short* __restrict__ biasP) {
    int bid = blockIdx.x;                       // grid 2048 = 16h * 8qblk * 16tile
    int h = bid >> 7, qblk = (bid >> 4) & 7, tile = bid & 15;
    int q0 = qblk * 128, kv0 = tile * 64;
    __shared__ short T[128][68];                // T[qrel][kvrel], 8B-aligned rows

    int t = threadIdx.x;
    {
        int qr = t >> 1, half = t & 1;
        const float* src = bias + ((size_t)h << 20) + (size_t)(q0 + qr) * 1024 + kv0 + half * 32;
#pragma unroll
        for (int i = 0; i < 32; i += 4) {
            float4 v = *(const float4*)(src + i);
            bf16x4 p = {f2bf(v.x * LOG2E), f2bf(v.y * LOG2E), f2bf(v.z * LOG2E), f2bf(v.w * LOG2E)};
            *(bf16x4*)&T[qr][half * 32 + i] = p;
        }
    }
    __syncthreads();

    int w = t >> 6, l = t & 63, lm = l & 15, lq = l >> 4;
    short* dst = biasP + (((size_t)(h * 16 + tile) * 8 + qblk) * 4 + w) * 2048 + l * 8;
#pragma unroll
    for (int j = 0; j < 4; j++) {
        bf16x4 a = *(const bf16x4*)&T[w * 32 + lm][j * 16 + lq * 4];        // qt=0
        bf16x4 b = *(const bf16x4*)&T[w * 32 + 16 + lm][j * 16 + lq * 4];   // qt=1
        bf16x8 o = {a[0], a[1], a[2], a[3], b[0], b[1], b[2], b[3]};
        *(bf16x8*)(dst + j * 512) = o;
    }
}

// ---------------------------------------------------------------------------
// Kernel 0b: weight fp32 -> bf16 (wv_w and out_w, both [n][k] row-major)
// ---------------------------------------------------------------------------
__global__ __launch_bounds__(256) void wconv(const float* __restrict__ wvw,
                                             const float* __restrict__ outw,
                                             short* __restrict__ wvwb,
                                             short* __restrict__ outwb) {
    int bid = blockIdx.x;
    const float* src = (bid < 512) ? wvw : outw;
    short* dst = (bid < 512) ? wvwb : outwb;
    int lb = (bid < 512) ? bid : bid - 512;
    size_t idx = ((size_t)lb * 256 + threadIdx.x) * 8;
    float4 a = *(const float4*)(src + idx);
    float4 b = *(const float4*)(src + idx + 4);
    bf16x8 t = {f2bf(a.x), f2bf(a.y), f2bf(a.z), f2bf(a.w),
                f2bf(b.x), f2bf(b.y), f2bf(b.z), f2bf(b.w)};
    *(bf16x8*)(dst + idx) = t;
}

// ---------------------------------------------------------------------------
// Kernel 1: xw = (x_h @ w_att_val[h]) * 0.125 * log2e (bf16)  AND  xbf = bf16(x)
// ---------------------------------------------------------------------------
__global__ __launch_bounds__(256) void xw_kernel(const float* __restrict__ x,
                                                 const float* __restrict__ watt,
                                                 short* __restrict__ xw,
                                                 short* __restrict__ xbf) {
    int bid = blockIdx.x;
    int q4 = bid & 3;
    int bh = bid >> 2;          // b*16 + h
    int h = bh & 15;
    __shared__ short Wt[64][88];   // W^T: Wt[e'][d]

    int tid = threadIdx.x;
    {
        const float* W = watt + (size_t)h * 4096;
        int idx = tid * 16;
        int d = idx >> 6, e0 = idx & 63;
#pragma unroll
        for (int i = 0; i < 16; i += 4) {
            float4 v = *(const float4*)(W + d * 64 + e0 + i);
            Wt[e0 + i + 0][d] = f2bf(v.x);
            Wt[e0 + i + 1][d] = f2bf(v.y);
            Wt[e0 + i + 2][d] = f2bf(v.z);
            Wt[e0 + i + 3][d] = f2bf(v.w);
        }
    }
    __syncthreads();

    int wave = tid >> 6, lane = tid & 63;
    int lm = lane & 15, lq = lane >> 4;

    bf16x8 bfr[4][2];
#pragma unroll
    for (int nt = 0; nt < 4; nt++)
#pragma unroll
        for (int kf = 0; kf < 2; kf++)
            bfr[nt][kf] = *(const bf16x8*)&Wt[nt * 16 + lm][kf * 32 + lq * 8];

    int b = bh >> 4;
    const float QSCALE = 0.125f * LOG2E;
    for (int pass = 0; pass < 4; pass++) {
        int p0 = q4 * 256 + pass * 64 + wave * 16;
        const float* xrow = x + ((size_t)(b * 1024 + p0 + lm)) * 1024 + h * 64;
        short* xorow = xbf + ((size_t)(b * 1024 + p0 + lm)) * 1024 + h * 64;
        bf16x8 af[2];
#pragma unroll
        for (int kf = 0; kf < 2; kf++) {
            float4 v0 = *(const float4*)(xrow + kf * 32 + lq * 8);
            float4 v1 = *(const float4*)(xrow + kf * 32 + lq * 8 + 4);
            bf16x8 t;
            t[0] = f2bf(v0.x); t[1] = f2bf(v0.y); t[2] = f2bf(v0.z); t[3] = f2bf(v0.w);
            t[4] = f2bf(v1.x); t[5] = f2bf(v1.y); t[6] = f2bf(v1.z); t[7] = f2bf(v1.w);
            af[kf] = t;
            *(bf16x8*)(xorow + kf * 32 + lq * 8) = t;   // bf16 copy of x
        }
#pragma unroll
        for (int nt = 0; nt < 4; nt++) {
            f32x4 acc = {0.f, 0.f, 0.f, 0.f};
            acc = __builtin_amdgcn_mfma_f32_16x16x32_bf16(af[0], bfr[nt][0], acc, 0, 0, 0);
            acc = __builtin_amdgcn_mfma_f32_16x16x32_bf16(af[1], bfr[nt][1], acc, 0, 0, 0);
            size_t base = ((size_t)bh * 1024 + p0 + lq * 4) * 64 + nt * 16 + lm;
#pragma unroll
            for (int r = 0; r < 4; r++)
                xw[base + (size_t)r * 64] = f2bf(acc[r] * QSCALE);
        }
    }
}

// ---------------------------------------------------------------------------
// Kernel 2: vt[b,h,d,p] = (x @ wv_w^T + wv_b) transposed (bf16), with the
// per-32-col permutation p' = g*8 + h2*4 + r so flash can read V fragments
// as single b128s. XCD-swizzled grid. 2-PHASE staging: double-buffered LDS,
// one barrier per K-step, next tile's global_load_lds issued right after
// the barrier so the vmcnt drain waits on loads a full K-step old.
// ---------------------------------------------------------------------------
__global__ __launch_bounds__(256) void vx_gemm(const short* __restrict__ xbf,
                                               const short* __restrict__ wvwb,
                                               const float* __restrict__ wvb,
                                               short* __restrict__ vt) {
    int logical = (blockIdx.x & 7) * 128 + (blockIdx.x >> 3);   // grid 1024 = 8*128
    int mblk = logical >> 3, nblk = logical & 7;
    int m0 = mblk * 128, n0 = nblk * 128;
    __shared__ short As[2][128 * 32];
    __shared__ short Bs[2][128 * 32];

    int tid = threadIdx.x;
    int wv = tid >> 6, ln = tid & 63;
    int c0 = wv * 2;
    int rrow = ln >> 2, rseg = (ln & 3) * 8;
    const short* gA = xbf + (size_t)(m0 + c0 * 16 + rrow) * 1024 + rseg;
    const short* gB = wvwb + (size_t)(n0 + c0 * 16 + rrow) * 1024 + rseg;

    int lane = ln, lm = lane & 15, lq = lane >> 4;
    int wm = (wv >> 1) * 64, wn = (wv & 1) * 64;

    f32x4 acc[4][4];
#pragma unroll
    for (int i = 0; i < 4; i++)
#pragma unroll
        for (int j = 0; j < 4; j++) acc[i][j] = (f32x4){0.f, 0.f, 0.f, 0.f};

    // prologue: issue tile 0 -> buf 0
    async16(gA, As[0] + c0 * 512);
    async16(gA + 16 * 1024, As[0] + c0 * 512 + 512);
    async16(gB, Bs[0] + c0 * 512);
    async16(gB + 16 * 1024, Bs[0] + c0 * 512 + 512);

    int cur = 0;
    for (int k0 = 0; k0 < 1024; k0 += 32) {
        __syncthreads();   // drains tile-k0 DMA (issued a full step ago) + frees buf^1
        if (k0 < 992) {
            int kn = k0 + 32;
            short* nA = As[cur ^ 1] + c0 * 512;
            short* nB = Bs[cur ^ 1] + c0 * 512;
            async16(gA + kn, nA);
            async16(gA + kn + 16 * 1024, nA + 512);
            async16(gB + kn, nB);
            async16(gB + kn + 16 * 1024, nB + 512);
        }
        bf16x8 af[4], bfr[4];
#pragma unroll
        for (int mt = 0; mt < 4; mt++) af[mt] = *(const bf16x8*)&As[cur][(wm + mt * 16 + lm) * 32 + lq * 8];
#pragma unroll
        for (int nt = 0; nt < 4; nt++) bfr[nt] = *(const bf16x8*)&Bs[cur][(wn + nt * 16 + lm) * 32 + lq * 8];
#pragma unroll
        for (int mt = 0; mt < 4; mt++)
#pragma unroll
            for (int nt = 0; nt < 4; nt++)
                acc[mt][nt] = __builtin_amdgcn_mfma_f32_16x16x32_bf16(af[mt], bfr[nt], acc[mt][nt], 0, 0, 0);
        cur ^= 1;
    }

#pragma unroll
    for (int nt = 0; nt < 4; nt++) {
        int e = n0 + wn + nt * 16 + lm;
        float bias = wvb[e];
        int hh = e >> 6, dd = e & 63;
#pragma unroll
        for (int mt = 0; mt < 4; mt++) {
            int pg = m0 + wm + mt * 16 + lq * 4;
            // V column permute within each 32-block: orig (h2=mt&1, g=lq, r)
            // stored at g*8 + h2*4 + r
            int ppn = (pg & ~31) + lq * 8 + (mt & 1) * 4;
            int bb = ppn >> 10, pp = ppn & 1023;
            bf16x4 pk;
#pragma unroll
            for (int r = 0; r < 4; r++) pk[r] = f2bf(acc[mt][nt][r] + bias);
            *(bf16x4*)(vt + ((size_t)((bb * 16 + hh) * 64 + dd)) * 1024 + pp) = pk;
        }
    }
}

// ---------------------------------------------------------------------------
// Kernel 3: flash attention v9 (frozen from round 6) — register-staged K/V
// dbuf, one LDS-only barrier/tile, P in registers, MFMA-ones row-sum,
// pre-blocked bf16 bias, permuted V, XCD swizzle.
// ---------------------------------------------------------------------------
__global__ __launch_bounds__(256, 3) void flash_kernel(const short* __restrict__ xbf,
                                                       const short* __restrict__ xw,
                                                       const short* __restrict__ vt,
                                                       const short* __restrict__ biasP,
                                                       short* __restrict__ obuf) {
    int logical = (blockIdx.x & 7) * 256 + (blockIdx.x >> 3);
    int qblk = logical & 7, b = (logical >> 3) & 15, h = logical >> 7;
    int bh = b * 16 + h;
    int q0 = qblk * 128;

    __shared__ short Ks[2][64 * 72];   // K[kv][d], row stride 72
    __shared__ short Vs[2][64 * 72];   // V^T[d][kv-permuted], row stride 72

    int tid = threadIdx.x, wave = tid >> 6, lane = tid & 63;
    int lm = lane & 15, lq = lane >> 4;

    // Q fragments: B-operand of the swapped QK^T (lane lm = q column).
    bf16x8 qa[2][2];
#pragma unroll
    for (int qt = 0; qt < 2; qt++)
#pragma unroll
        for (int kf = 0; kf < 2; kf++)
            qa[qt][kf] = *(const bf16x8*)(xw + ((size_t)bh * 1024 + q0 + wave * 32 + qt * 16 + lm) * 64 + kf * 32 + lq * 8);

    f32x4 o[2][4];
#pragma unroll
    for (int qt = 0; qt < 2; qt++)
#pragma unroll
        for (int dt = 0; dt < 4; dt++) o[qt][dt] = (f32x4){0.f, 0.f, 0.f, 0.f};
    // row-sum accumulators on the MFMA pipe: osum[qt][r] = sum_kv P for
    // q = qt*16 + lq*4 + r (value replicated across lm columns)
    f32x4 osum[2];
    osum[0] = (f32x4){0.f, 0.f, 0.f, 0.f};
    osum[1] = (f32x4){0.f, 0.f, 0.f, 0.f};
    const short ONE = 0x3F80;          // 1.0 bf16
    const bf16x8 vones = {ONE, ONE, ONE, ONE, ONE, ONE, ONE, ONE};

    // staging maps: thread stages 2x bf16x8 for K and 2 for V
    int ci0 = tid * 2, ci1 = tid * 2 + 1;
    int r0 = ci0 >> 3, s0 = (ci0 & 7) * 8;
    int r1 = ci1 >> 3, s1 = (ci1 & 7) * 8;
    const short* kg = xbf + ((size_t)(b * 1024)) * 1024 + h * 64;   // + (kv0+row)*1024 + seg
    const short* vg = vt + ((size_t)bh * 64) * 1024;                // + row*1024 + kv0 + seg
    // pre-blocked bf16 bias: per tile, 4 coalesced 16B loads per thread
    const short* bg = biasP + (((size_t)(h * 16) * 8 + qblk) * 4 + wave) * 2048 + lane * 8;
    const size_t BT_STRIDE = 65536;   // 8qblk*4wave*2048 shorts per tile

    bf16x8 kr[2], vr[2], br[4];
    // prologue: tile 0 -> LDS buf0; tile 1 -> regs; bias tile 0 -> regs
    kr[0] = *(const bf16x8*)(kg + (size_t)r0 * 1024 + s0);
    kr[1] = *(const bf16x8*)(kg + (size_t)r1 * 1024 + s1);
    vr[0] = *(const bf16x8*)(vg + (size_t)r0 * 1024 + s0);
    vr[1] = *(const bf16x8*)(vg + (size_t)r1 * 1024 + s1);
    *(bf16x8*)&Ks[0][r0 * 72 + s0] = kr[0];
    *(bf16x8*)&Ks[0][r1 * 72 + s1] = kr[1];
    *(bf16x8*)&Vs[0][r0 * 72 + s0] = vr[0];
    *(bf16x8*)&Vs[0][r1 * 72 + s1] = vr[1];
    kr[0] = *(const bf16x8*)(kg + (size_t)(64 + r0) * 1024 + s0);
    kr[1] = *(const bf16x8*)(kg + (size_t)(64 + r1) * 1024 + s1);
    vr[0] = *(const bf16x8*)(vg + (size_t)r0 * 1024 + 64 + s0);
    vr[1] = *(const bf16x8*)(vg + (size_t)r1 * 1024 + 64 + s1);
#pragma unroll
    for (int kt = 0; kt < 4; kt++)
        br[kt] = *(const bf16x8*)(bg + kt * 512);

    for (int tile = 0; tile < 16; tile++) {
        const int cur = tile & 1;
        const short* Kc = Ks[cur];
        const short* Vc = Vs[cur];
        short* Kn = Ks[cur ^ 1];
        short* Vn = Vs[cur ^ 1];

        barrier_lds();   // separates last-readers of buf[cur^1] from its writers

        // stage tile+1 (in regs) into the other buffer
        if (tile < 15) {
            *(bf16x8*)&Kn[r0 * 72 + s0] = kr[0];
            *(bf16x8*)&Kn[r1 * 72 + s1] = kr[1];
            *(bf16x8*)&Vn[r0 * 72 + s0] = vr[0];
            *(bf16x8*)&Vn[r1 * 72 + s1] = vr[1];
        }
        // issue tile+2 global loads (consumed at next iter's stage)
        if (tile < 14) {
            int kvn = (tile + 2) * 64;
            kr[0] = *(const bf16x8*)(kg + (size_t)(kvn + r0) * 1024 + s0);
            kr[1] = *(const bf16x8*)(kg + (size_t)(kvn + r1) * 1024 + s1);
            vr[0] = *(const bf16x8*)(vg + (size_t)r0 * 1024 + kvn + s0);
            vr[1] = *(const bf16x8*)(vg + (size_t)r1 * 1024 + kvn + s1);
        }

        // acc init from prefetched bias regs:
        // s[kt][qt] elem r -> (kv = kv0+kt*16+lq*4+r, q = q0+wave*32+qt*16+lm)
        f32x4 s[4][2];
#pragma unroll
        for (int kt = 0; kt < 4; kt++)
#pragma unroll
            for (int qt = 0; qt < 2; qt++)
                s[kt][qt] = (f32x4){bf2f(br[kt][qt * 4 + 0]), bf2f(br[kt][qt * 4 + 1]),
                                    bf2f(br[kt][qt * 4 + 2]), bf2f(br[kt][qt * 4 + 3])};

        // issue next tile's bias ASAP (br just consumed; T14 issue-early)
        if (tile < 15) {
            const short* bgn = bg + (size_t)(tile + 1) * BT_STRIDE;
#pragma unroll
            for (int kt = 0; kt < 4; kt++)
                br[kt] = *(const bf16x8*)(bgn + kt * 512);
        }

        // S^T = K Q^T + bias  (A = K rows=kv, B = Q cols=q)
#pragma unroll
        for (int kf = 0; kf < 2; kf++) {
            bf16x8 ka[4];
#pragma unroll
            for (int kt = 0; kt < 4; kt++)
                ka[kt] = *(const bf16x8*)&Kc[(kt * 16 + lm) * 72 + kf * 32 + lq * 8];
#pragma unroll
            for (int kt = 0; kt < 4; kt++)
#pragma unroll
                for (int qt = 0; qt < 2; qt++)
                    s[kt][qt] = __builtin_amdgcn_mfma_f32_16x16x32_bf16(ka[kt], qa[qt][kf], s[kt][qt], 0, 0, 0);
        }

        // fixed-max softmax in place: p = exp2(s)  (denominator comes from
        // the ones-MFMA below)
#pragma unroll
        for (int kt = 0; kt < 4; kt++)
#pragma unroll
            for (int qt = 0; qt < 2; qt++) {
                s[kt][qt][0] = __builtin_amdgcn_exp2f(s[kt][qt][0]);
                s[kt][qt][1] = __builtin_amdgcn_exp2f(s[kt][qt][1]);
                s[kt][qt][2] = __builtin_amdgcn_exp2f(s[kt][qt][2]);
                s[kt][qt][3] = __builtin_amdgcn_exp2f(s[kt][qt][3]);
            }

        // O += P V; osum += P @ ones.  P stays in registers; V stored
        // permuted so the matching fragment is ONE b128 at col kf*32 + lq*8.
#pragma unroll
        for (int kf = 0; kf < 2; kf++) {
            bf16x8 pa[2];
#pragma unroll
            for (int qt = 0; qt < 2; qt++) {
                U8 u;
                u.u[0] = cvtpk(s[kf * 2][qt][0], s[kf * 2][qt][1]);
                u.u[1] = cvtpk(s[kf * 2][qt][2], s[kf * 2][qt][3]);
                u.u[2] = cvtpk(s[kf * 2 + 1][qt][0], s[kf * 2 + 1][qt][1]);
                u.u[3] = cvtpk(s[kf * 2 + 1][qt][2], s[kf * 2 + 1][qt][3]);
                pa[qt] = u.v;
                osum[qt] = __builtin_amdgcn_mfma_f32_16x16x32_bf16(pa[qt], vones, osum[qt], 0, 0, 0);
            }
#pragma unroll
            for (int dt = 0; dt < 4; dt++) {
                bf16x8 uv = *(const bf16x8*)&Vc[(dt * 16 + lm) * 72 + kf * 32 + lq * 8];
#pragma unroll
                for (int qt = 0; qt < 2; qt++)
                    o[qt][dt] = __builtin_amdgcn_mfma_f32_16x16x32_bf16(pa[qt], uv, o[qt][dt], 0, 0, 0);
            }
        }
    }

    // epilogue: osum[qt][r] already holds the denominator for
    // q = qt*16 + lq*4 + r (same D-layout as o). No shuffle, no LDS, no sync.
#pragma unroll
    for (int qt = 0; qt < 2; qt++) {
        float inv[4];
#pragma unroll
        for (int r = 0; r < 4; r++)
            inv[r] = 1.f / osum[qt][r];
#pragma unroll
        for (int dt = 0; dt < 4; dt++) {
            int e = h * 64 + dt * 16 + lm;
#pragma unroll
            for (int r = 0; r < 4; r++) {
                int p = q0 + wave * 32 + qt * 16 + lq * 4 + r;
                obuf[((size_t)(b * 1024 + p)) * 1024 + e] = f2bf(o[qt][dt][r] * inv[r]);
            }
        }
    }
}

// ---------------------------------------------------------------------------
// Kernel 4: out = obuf @ out_w^T + out_b (fp32). 2-phase dbuf staging,
// XCD-swizzled grid.
// ---------------------------------------------------------------------------
__global__ __launch_bounds__(256) void out_gemm(const short* __restrict__ obuf,
                                                const short* __restrict__ outwb,
                                                const float* __restrict__ outb,
                                                float* __restrict__ out) {
    int logical = (blockIdx.x & 7) * 128 + (blockIdx.x >> 3);
    int mblk = logical >> 3, nblk = logical & 7;
    int m0 = mblk * 128, n0 = nblk * 128;
    __shared__ short As[2][128 * 32];
    __shared__ short Bs[2][128 * 32];

    int tid = threadIdx.x;
    int wv = tid >> 6, ln = tid & 63;
    int c0 = wv * 2;
    int rrow = ln >> 2, rseg = (ln & 3) * 8;
    const short* gA = obuf + (size_t)(m0 + c0 * 16 + rrow) * 1024 + rseg;
    const short* gB = outwb + (size_t)(n0 + c0 * 16 + rrow) * 1024 + rseg;

    int lm = ln & 15, lq = ln >> 4;
    int wm = (wv >> 1) * 64, wn = (wv & 1) * 64;

    f32x4 acc[4][4];
#pragma unroll
    for (int i = 0; i < 4; i++)
#pragma unroll
        for (int j = 0; j < 4; j++) acc[i][j] = (f32x4){0.f, 0.f, 0.f, 0.f};

    // prologue: issue tile 0 -> buf 0
    async16(gA, As[0] + c0 * 512);
    async16(gA + 16 * 1024, As[0] + c0 * 512 + 512);
    async16(gB, Bs[0] + c0 * 512);
    async16(gB + 16 * 1024, Bs[0] + c0 * 512 + 512);

    int cur = 0;
    for (int k0 = 0; k0 < 1024; k0 += 32) {
        __syncthreads();   // drains tile-k0 DMA (issued a full step ago) + frees buf^1
        if (k0 < 992) {
            int kn = k0 + 32;
            short* nA = As[cur ^ 1] + c0 * 512;
            short* nB = Bs[cur ^ 1] + c0 * 512;
            async16(gA + kn, nA);
            async16(gA + kn + 16 * 1024, nA + 512);
            async16(gB + kn, nB);
            async16(gB + kn + 16 * 1024, nB + 512);
        }
        bf16x8 af[4], bfr[4];
#pragma unroll
        for (int mt = 0; mt < 4; mt++) af[mt] = *(const bf16x8*)&As[cur][(wm + mt * 16 + lm) * 32 + lq * 8];
#pragma unroll
        for (int nt = 0; nt < 4; nt++) bfr[nt] = *(const bf16x8*)&Bs[cur][(wn + nt * 16 + lm) * 32 + lq * 8];
#pragma unroll
        for (int mt = 0; mt < 4; mt++)
#pragma unroll
            for (int nt = 0; nt < 4; nt++)
                acc[mt][nt] = __builtin_amdgcn_mfma_f32_16x16x32_bf16(af[mt], bfr[nt], acc[mt][nt], 0, 0, 0);
        cur ^= 1;
    }

#pragma unroll
    for (int nt = 0; nt < 4; nt++) {
        int e = n0 + wn + nt * 16 + lm;
        float bias = outb[e];
#pragma unroll
        for (int mt = 0; mt < 4; mt++) {
            int pg = m0 + wm + mt * 16 + lq * 4;
#pragma unroll
            for (int r = 0; r < 4; r++)
                out[(size_t)(pg + r) * 1024 + e] = acc[mt][nt][r] + bias;
        }
    }
}

extern "C" void kernel_launch(void* const* d_in, const int* in_sizes, int n_in,
                              void* d_out, int out_size, void* d_ws, size_t ws_size,
                              hipStream_t stream) {
    const float* x    = (const float*)d_in[0];  // [16,1024,1024]
    const float* watt = (const float*)d_in[1];  // [16,64,64]
    const float* bias = (const float*)d_in[2];  // [16,1024,1024]
    const float* wvw  = (const float*)d_in[3];  // [1024,1024]
    const float* wvb  = (const float*)d_in[4];  // [1024]
    const float* outw = (const float*)d_in[5];  // [1024,1024]
    const float* outb = (const float*)d_in[6];  // [1024]
    float* out = (float*)d_out;

    char* ws = (char*)d_ws;
    short* xw     = (short*)ws;                           // 32 MB  [B,H,P,DH] bf16 (Q, pre-scaled 0.125*log2e)
    short* vt     = (short*)(ws + ((size_t)32 << 20));    // 32 MB  [B,H,DH,P] bf16 (V^T, col-permuted)
    short* obuf   = (short*)(ws + ((size_t)64 << 20));    // 32 MB  [B,P,E]    bf16 (attn out)
    short* xbf    = (short*)(ws + ((size_t)96 << 20));    // 32 MB  [B,P,E]    bf16 (x)
    short* biasP  = (short*)(ws + ((size_t)128 << 20));   // 32 MB  blocked bf16 bias*log2e
    short* wvwb   = (short*)(ws + ((size_t)160 << 20));   // 2 MB
    short* outwb  = (short*)(ws + ((size_t)162 << 20));   // 2 MB

    xw_kernel<<<PB * PH * 4, 256, 0, stream>>>(x, watt, xw, xbf);
    bias_prep<<<2048, 256, 0, stream>>>(bias, biasP);
    wconv<<<1024, 256, 0, stream>>>(wvw, outw, wvwb, outwb);
    vx_gemm<<<(PB * PP / 128) * (PE / 128), 256, 0, stream>>>(xbf, wvwb, wvb, vt);
    flash_kernel<<<PB * PH * (PP / 128), 256, 0, stream>>>(xbf, xw, vt, biasP, obuf);
    out_gemm<<<(PB * PP / 128) * (PE / 128), 256, 0, stream>>>(obuf, outwb, outb, out);
}